// Round 14
// baseline (413.823 us; speedup 1.0000x reference)
//
#include <hip/hip_runtime.h>

#define DEV __device__ __forceinline__

typedef __attribute__((ext_vector_type(8))) short short8;
typedef __attribute__((ext_vector_type(4))) float floatx4;
typedef __attribute__((ext_vector_type(16))) float floatx16;
typedef __attribute__((ext_vector_type(4))) unsigned short ushort4v;
typedef __attribute__((ext_vector_type(8))) unsigned short ushort8v;

// ---------- sizes ----------
#define Bz 4096
#define Dz 256
#define Nz 128
#define Fz 128
#define Oz 256

// ---------- workspace layout (bytes) ----------
static constexpr size_t OFF_CONN = 0;                                   // 32 KB bf16 conn
static constexpr size_t OFF_WT   = 65536;                               // WT[n][c:128][k:384] bf16
static constexpr size_t SZ_WT    = (size_t)Nz * 128 * 384 * 2;          // 12582912
static constexpr size_t OFF_OWT  = OFF_WT + SZ_WT;                      // out_wT[o:256][f:128] bf16 (64 KB)
static constexpr size_t OFF_XB   = OFF_OWT + 65536;                     // x bf16 (4096x256, 2 MB)
static constexpr size_t OFF_FIN  = OFF_XB + (size_t)Bz * Dz * 2;        // final bf16 (4096x128, 1 MB)
static constexpr size_t OFF_ST   = OFF_FIN + (size_t)Bz * Fz * 2;       // state bf16 [n][b][f] (128 MB)

// ---------- helpers ----------
DEV unsigned short f2bf(float x) {
    unsigned u = __float_as_uint(x);
    u = (u + 0x7FFFu + ((u >> 16) & 1u)) >> 16;
    return (unsigned short)u;
}
DEV float bf2f(unsigned short h) {
    return __uint_as_float(((unsigned)h) << 16);
}

typedef const __attribute__((address_space(1))) void cglobal_void;
typedef __attribute__((address_space(3))) void lds_void;

DEV void gld_lds16(const void* g, void* l) {
    __builtin_amdgcn_global_load_lds((cglobal_void*)g, (lds_void*)l, 16, 0, 0);
}

// ---------- K_PREP: all 4 prep ops in one launch (block-range dispatch) ----------
__global__ __launch_bounds__(256) void k_prep(const float* __restrict__ nw, unsigned short* __restrict__ WT,
                                              const float* __restrict__ ow, unsigned short* __restrict__ OWT,
                                              const float* __restrict__ x, unsigned short* __restrict__ XB,
                                              const float* __restrict__ att, unsigned short* __restrict__ conn) {
    __shared__ float ld[32][36];
    int bid = blockIdx.x, t = threadIdx.x;
    if (bid < 6144) {
        int batch = bid / 48, rem = bid % 48;
        int rt = rem / 4, ct = rem % 4;
        int kr = t >> 3, c4 = (t & 7) * 4;
        float4 v = *(const float4*)&nw[(size_t)batch * (384 * 128) + (size_t)(rt * 32 + kr) * 128 + ct * 32 + c4];
        ld[kr][c4 + 0] = v.x; ld[kr][c4 + 1] = v.y; ld[kr][c4 + 2] = v.z; ld[kr][c4 + 3] = v.w;
        __syncthreads();
        ushort4v o;
        o[0] = f2bf(ld[c4 + 0][kr]);
        o[1] = f2bf(ld[c4 + 1][kr]);
        o[2] = f2bf(ld[c4 + 2][kr]);
        o[3] = f2bf(ld[c4 + 3][kr]);
        *(ushort4v*)&WT[(size_t)batch * (128 * 384) + (size_t)(ct * 32 + kr) * 384 + rt * 32 + c4] = o;
    } else if (bid < 6176) {
        int rem = bid - 6144;
        int rt = rem / 8, ct = rem % 8;
        int kr = t >> 3, c4 = (t & 7) * 4;
        float4 v = *(const float4*)&ow[(size_t)(rt * 32 + kr) * 256 + ct * 32 + c4];
        ld[kr][c4 + 0] = v.x; ld[kr][c4 + 1] = v.y; ld[kr][c4 + 2] = v.z; ld[kr][c4 + 3] = v.w;
        __syncthreads();
        ushort4v o;
        o[0] = f2bf(ld[c4 + 0][kr]);
        o[1] = f2bf(ld[c4 + 1][kr]);
        o[2] = f2bf(ld[c4 + 2][kr]);
        o[3] = f2bf(ld[c4 + 3][kr]);
        *(ushort4v*)&OWT[(size_t)(ct * 32 + kr) * 128 + rt * 32 + c4] = o;
    } else if (bid < 7200) {
        size_t idx = ((size_t)(bid - 6176) * 256 + t) * 4;
        float4 v = *(const float4*)&x[idx];
        ushort4v o;
        o[0] = f2bf(v.x); o[1] = f2bf(v.y); o[2] = f2bf(v.z); o[3] = f2bf(v.w);
        *(ushort4v*)&XB[idx] = o;
    } else if (t < 64) {
        int i = bid - 7200;
        float a0 = att[i * 128 + t];
        float a1 = att[i * 128 + 64 + t];
        float m = fmaxf(a0, a1);
        for (int o = 32; o > 0; o >>= 1) m = fmaxf(m, __shfl_down(m, o));
        m = __shfl(m, 0);
        float e0 = __expf(a0 - m), e1 = __expf(a1 - m);
        float s = e0 + e1;
        for (int o = 32; o > 0; o >>= 1) s += __shfl_down(s, o);
        s = __shfl(s, 0);
        float inv = 1.f / s;
        conn[i * 128 + t] = f2bf(e0 * inv);
        conn[i * 128 + 64 + t] = f2bf(e1 * inv);
    }
}

// ---------- K2 (in-place): ST[i][b][f] = sum_j conn[i][j] * ST[j][b][f] ----------
// Round-8 v4 (52.5 µs measured; ~81% of BW floor). Unchanged (passing).
__global__ __launch_bounds__(256) void k2_agg(const unsigned short* __restrict__ conn,
                                              unsigned short* __restrict__ ST) {
    __shared__ unsigned short lA[128 * 136];   // conn, padded rows (+8); reused as out tile
    __shared__ unsigned short lB[2][32 * 128]; // double-buffered states tile [j][f]
    int b = blockIdx.x;
    int t = threadIdx.x, wid = t >> 6, lane = t & 63, q = lane >> 4, cc = lane & 15;
    int wm = (wid >> 1) << 6, wn = (wid & 1) << 6;

    auto STG = [&](int bufi, int kt) {
#pragma unroll
        for (int it = 0; it < 2; it++) {
            int g = it * 256 + t;
            int j = g >> 4, fg = g & 15;
            int lofs = __builtin_amdgcn_readfirstlane((it * 256 + (wid << 6)) * 8);
            gld_lds16(ST + ((size_t)(kt * 32 + j) * Bz + b) * Fz + fg * 8, &lB[bufi][0] + lofs);
        }
    };
    STG(0, 0);
    STG(1, 1);

#pragma unroll
    for (int it = 0; it < 8; it++) {
        int g = it * 256 + t;
        int row = g >> 4, cg = g & 15;
        *(short8*)&lA[row * 136 + cg * 8] = *(const short8*)&conn[row * 128 + cg * 8];
    }
    floatx4 acc[4][4];
#pragma unroll
    for (int mt = 0; mt < 4; mt++)
#pragma unroll
        for (int nt = 0; nt < 4; nt++) acc[mt][nt] = (floatx4){0.f, 0.f, 0.f, 0.f};

    for (int kt = 0; kt < 4; kt++) {
        int cur = kt & 1;
        if (kt < 3) asm volatile("s_waitcnt vmcnt(2) lgkmcnt(0)" ::: "memory");
        else        asm volatile("s_waitcnt vmcnt(0) lgkmcnt(0)" ::: "memory");
        __builtin_amdgcn_s_barrier();
        short8 af[4];
#pragma unroll
        for (int mt = 0; mt < 4; mt++)
            af[mt] = *(const short8*)&lA[(wm + mt * 16 + cc) * 136 + kt * 32 + q * 8];
        short8 bf[4];
#pragma unroll
        for (int nt = 0; nt < 4; nt++) {
            short8 v;
#pragma unroll
            for (int e = 0; e < 8; e++)
                v[e] = (short)lB[cur][(q * 8 + e) * 128 + wn + nt * 16 + cc];
            bf[nt] = v;
        }
#pragma unroll
        for (int mt = 0; mt < 4; mt++)
#pragma unroll
            for (int nt = 0; nt < 4; nt++)
                acc[mt][nt] = __builtin_amdgcn_mfma_f32_16x16x32_bf16(af[mt], bf[nt], acc[mt][nt], 0, 0, 0);
        __builtin_amdgcn_s_barrier();          // all waves done reading lB[cur]
        if (kt + 2 < 4) STG(cur, kt + 2);      // overwrite freed buffer
    }

    // epilogue: stage XOR-swizzled [i][f] tile in lA, then coalesced 16B row stores
#pragma unroll
    for (int mt = 0; mt < 4; mt++)
#pragma unroll
        for (int nt = 0; nt < 4; nt++) {
            int f = wn + nt * 16 + cc;
#pragma unroll
            for (int r = 0; r < 4; r++) {
                int il = wm + mt * 16 + q * 4 + r;
                lA[il * 128 + (f ^ ((il & 7) << 3))] = f2bf(acc[mt][nt][r]);
            }
        }
    __syncthreads();
#pragma unroll
    for (int it = 0; it < 8; it++) {
        int idx = it * 256 + t;
        int il = idx >> 4, ch = idx & 15;
        int sch = ch ^ (il & 7);
        ushort8v v = *(const ushort8v*)&lA[il * 128 + sch * 8];
        *(ushort8v*)&ST[((size_t)il * Bz + b) * Fz + ch * 8] = v;
    }
}

// ---------- K3 fused (in-place): ST[n] = relu([agg | x] @ W[n] + bias) ----------
// v11: 128x128 tile, 256 thr / 4 waves, wave tile 64x64 as 2x2 grid of 32x32
// accumulators using mfma_f32_32x32x16_bf16. LDS-read instr per block-step drops
// 48 -> 32 b128 (32 KFLOP/read vs 21K) — attacks the measured per-CU LDS
// throughput binder (per-step cost invariant across all other structure).
// Fragment map (generalizes working 16x16 pattern): A row=lane&31,
// k=(lane>>5)*8; B col=lane&31 symmetric. C/D: col=lane&31,
// row=(reg&3)+8*(reg>>2)+4*(lane>>5)  [measured m74/m101].
// Staging/sync: round-2 proven 4-gld/thread, 2 buffers, counted vmcnt(4).
// In-place safe: all ST reads precede writes; blocks disjoint (n, bt).
template <int KT0>
__global__ __launch_bounds__(256) void k3_fused(unsigned short* __restrict__ ST,
                                                const unsigned short* __restrict__ XB,
                                                const unsigned short* __restrict__ WT,
                                                const float* __restrict__ nb) {
    __shared__ unsigned short lds[2][2][128 * 32];  // [buf][A=0/B=1][row*32+k] — 32 KB
    int n = blockIdx.x >> 5, bt = blockIdx.x & 31;
    int t = threadIdx.x, wid = t >> 6, lane = t & 63;
    int r32 = lane & 31, kh = lane >> 5;            // row-in-32, k-half (0/1)
    int wm = (wid >> 1) << 6, wn = (wid & 1) << 6;  // 2x2 wave grid of 64x64 tiles

    const unsigned short* Sg = ST + ((size_t)n * Bz + bt * 128) * Fz;   // ld Fz
    const unsigned short* Xg = XB + (size_t)bt * 128 * Dz;              // ld Dz
    const unsigned short* Bg = WT + (size_t)n * 128 * 384;              // ld 384

    floatx16 acc[2][2];
#pragma unroll
    for (int mt = 0; mt < 2; mt++)
#pragma unroll
        for (int nt = 0; nt < 2; nt++)
#pragma unroll
            for (int e = 0; e < 16; e++) acc[mt][nt][e] = 0.f;

    auto STAGE = [&](int bufi, int kt) {
#pragma unroll
        for (int it = 0; it < 2; it++) {
            int g = it * 256 + t;
            int row = g >> 2, kg = g & 3;
            int lofs = __builtin_amdgcn_readfirstlane((it * 256 + (wid << 6)) * 8);
            if (kt < 4)
                gld_lds16(Sg + (size_t)row * Fz + kt * 32 + kg * 8, &lds[bufi][0][0] + lofs);
            else
                gld_lds16(Xg + (size_t)row * Dz + (kt - 4) * 32 + kg * 8, &lds[bufi][0][0] + lofs);
            gld_lds16(Bg + (size_t)row * 384 + kt * 32 + kg * 8, &lds[bufi][1][0] + lofs);
        }
    };
    STAGE(0, KT0);
    STAGE(1, KT0 + 1);

#pragma unroll
    for (int kt = KT0; kt < 12; kt++) {
        int cur = (kt - KT0) & 1;
        // oldest 4 gld (stage kt) retired; stage kt+1's 4 stay in flight.
        if (kt < 11) asm volatile("s_waitcnt vmcnt(4) lgkmcnt(0)" ::: "memory");
        else         asm volatile("s_waitcnt vmcnt(0) lgkmcnt(0)" ::: "memory");
        __builtin_amdgcn_s_barrier();
        __builtin_amdgcn_sched_barrier(0);
        short8 af[2][2], bfr[2][2];   // [kq][tile]
#pragma unroll
        for (int kq = 0; kq < 2; kq++) {
#pragma unroll
            for (int mt = 0; mt < 2; mt++)
                af[kq][mt] = *(const short8*)&lds[cur][0][(wm + mt * 32 + r32) * 32 + kq * 16 + kh * 8];
#pragma unroll
            for (int nt = 0; nt < 2; nt++)
                bfr[kq][nt] = *(const short8*)&lds[cur][1][(wn + nt * 32 + r32) * 32 + kq * 16 + kh * 8];
        }
#pragma unroll
        for (int kq = 0; kq < 2; kq++)
#pragma unroll
            for (int mt = 0; mt < 2; mt++)
#pragma unroll
                for (int nt = 0; nt < 2; nt++)
                    acc[mt][nt] = __builtin_amdgcn_mfma_f32_32x32x16_bf16(af[kq][mt], bfr[kq][nt], acc[mt][nt], 0, 0, 0);
        __builtin_amdgcn_sched_barrier(0);
        __builtin_amdgcn_s_barrier();           // all waves done reading lds[cur]
        if (kt + 2 < 12) STAGE(cur, kt + 2);    // overwrite freed buffer
    }

    // epilogue: bias+relu -> XOR-swizzled [b_local][f] tile (all 32 KB of lds),
    // then coalesced 16B contiguous stores. C/D map: col=r32, row=(reg&3)+8*(reg>>2)+4*kh.
    __syncthreads();
    unsigned short* outT = &lds[0][0][0];
#pragma unroll
    for (int nt = 0; nt < 2; nt++) {
        int f = wn + nt * 32 + r32;
        float bias = nb[n * Fz + f];
#pragma unroll
        for (int mt = 0; mt < 2; mt++) {
#pragma unroll
            for (int reg = 0; reg < 16; reg++) {
                int bl = wm + mt * 32 + (reg & 3) + 8 * (reg >> 2) + 4 * kh;
                float v = acc[mt][nt][reg] + bias;
                outT[bl * 128 + (f ^ ((bl & 7) << 3))] = f2bf(v > 0.f ? v : 0.f);
            }
        }
    }
    __syncthreads();
    size_t base = ((size_t)n * Bz + (size_t)bt * 128) * Fz;
#pragma unroll
    for (int it = 0; it < 8; it++) {
        int idx = it * 256 + t;
        int bl = idx >> 4, ch = idx & 15;
        int sch = ch ^ (bl & 7);
        ushort8v v = *(const ushort8v*)&outT[bl * 128 + sch * 8];
        *(ushort8v*)&ST[base + (size_t)idx * 8] = v;
    }
}

// ---------- K4: final[b][f] = mean_n ST[n][b][f] ----------
__global__ __launch_bounds__(256) void k4_mean(const unsigned short* __restrict__ S,
                                               unsigned short* __restrict__ fin) {
    int t = threadIdx.x;
    size_t base = (size_t)blockIdx.x * 2048 + (size_t)t * 8;
    float a[8] = {0.f, 0.f, 0.f, 0.f, 0.f, 0.f, 0.f, 0.f};
#pragma unroll 8
    for (int n = 0; n < Nz; n++) {
        ushort8v v = *(const ushort8v*)&S[(size_t)n * Bz * Fz + base];
#pragma unroll
        for (int e = 0; e < 8; e++) a[e] += bf2f(v[e]);
    }
    ushort8v o;
#pragma unroll
    for (int e = 0; e < 8; e++) o[e] = f2bf(a[e] * (1.f / 128.f));
    *(ushort8v*)&fin[base] = o;
}

// ---------- K5: out = final @ out_w + out_b (fp32 out) ----------
__global__ __launch_bounds__(256) void k5_out(const unsigned short* __restrict__ fin,
                                              const unsigned short* __restrict__ owt,
                                              const float* __restrict__ ob,
                                              float* __restrict__ out) {
    __shared__ unsigned short lA[128 * 32];
    __shared__ unsigned short lB[128 * 32];
    int bt = blockIdx.x >> 1, ct = blockIdx.x & 1;
    int t = threadIdx.x, wid = t >> 6, lane = t & 63, q = lane >> 4, cc = lane & 15;
    int wm = (wid >> 1) << 6, wn = (wid & 1) << 6;

    const unsigned short* Ag = fin + (size_t)bt * 128 * Fz;
    const unsigned short* Bg = owt + (size_t)ct * 128 * Fz;

    floatx4 acc[4][4];
#pragma unroll
    for (int mt = 0; mt < 4; mt++)
#pragma unroll
        for (int nt = 0; nt < 4; nt++) acc[mt][nt] = (floatx4){0.f, 0.f, 0.f, 0.f};

    for (int kt = 0; kt < 4; kt++) {
#pragma unroll
        for (int it = 0; it < 2; it++) {
            int g = it * 256 + t;
            int row = g >> 2, kg = g & 3;
            int lofs = __builtin_amdgcn_readfirstlane((it * 256 + (wid << 6)) * 8);
            gld_lds16(Ag + (size_t)row * Fz + kt * 32 + kg * 8, lA + lofs);
            gld_lds16(Bg + (size_t)row * Fz + kt * 32 + kg * 8, lB + lofs);
        }
        __syncthreads();
        short8 af[4], bfr[4];
#pragma unroll
        for (int mt = 0; mt < 4; mt++)
            af[mt] = *(const short8*)&lA[(wm + mt * 16 + cc) * 32 + q * 8];
#pragma unroll
        for (int nt = 0; nt < 4; nt++)
            bfr[nt] = *(const short8*)&lB[(wn + nt * 16 + cc) * 32 + q * 8];
#pragma unroll
        for (int mt = 0; mt < 4; mt++)
#pragma unroll
            for (int nt = 0; nt < 4; nt++)
                acc[mt][nt] = __builtin_amdgcn_mfma_f32_16x16x32_bf16(af[mt], bfr[nt], acc[mt][nt], 0, 0, 0);
        __syncthreads();
    }
#pragma unroll
    for (int nt = 0; nt < 4; nt++) {
        int o = ct * 128 + wn + nt * 16 + cc;
        float bias = ob[o];
#pragma unroll
        for (int mt = 0; mt < 4; mt++) {
#pragma unroll
            for (int r = 0; r < 4; r++) {
                int b = bt * 128 + wm + mt * 16 + q * 4 + r;
                out[(size_t)b * Oz + o] = acc[mt][nt][r] + bias;
            }
        }
    }
}

extern "C" void kernel_launch(void* const* d_in, const int* in_sizes, int n_in,
                              void* d_out, int out_size, void* d_ws, size_t ws_size,
                              hipStream_t stream) {
    const float* x = (const float*)d_in[0];
    const float* nw = (const float*)d_in[1];
    const float* nb = (const float*)d_in[2];
    const float* att = (const float*)d_in[3];
    const float* ow = (const float*)d_in[4];
    const float* ob = (const float*)d_in[5];
    char* ws = (char*)d_ws;
    unsigned short* CONN = (unsigned short*)(ws + OFF_CONN);
    unsigned short* WT = (unsigned short*)(ws + OFF_WT);
    unsigned short* OWT = (unsigned short*)(ws + OFF_OWT);
    unsigned short* XB = (unsigned short*)(ws + OFF_XB);
    unsigned short* FIN = (unsigned short*)(ws + OFF_FIN);
    unsigned short* ST = (unsigned short*)(ws + OFF_ST);
    float* out = (float*)d_out;

    // prep: one launch for softmax + both transposes + convert
    k_prep<<<7328, 256, 0, stream>>>(nw, WT, ow, OWT, x, XB, att, CONN);

    // iteration 1: ST = relu(x @ W_x + b)   (state0 == 0 -> skip state k-steps)
    k3_fused<4><<<Nz * 32, 256, 0, stream>>>(ST, XB, WT, nb);

    // iterations 2 and 3: in-place agg then fused update
    for (int it = 0; it < 2; it++) {
        k2_agg<<<Bz, 256, 0, stream>>>(CONN, ST);
        k3_fused<0><<<Nz * 32, 256, 0, stream>>>(ST, XB, WT, nb);
    }

    k4_mean<<<(Bz * Fz) / 2048, 256, 0, stream>>>(ST, FIN);
    k5_out<<<64, 256, 0, stream>>>(FIN, OWT, ob, out);
}

// Round 15
// 411.235 us; speedup vs baseline: 1.0063x; 1.0063x over previous
//
#include <hip/hip_runtime.h>

#define DEV __device__ __forceinline__

typedef __attribute__((ext_vector_type(8))) short short8;
typedef __attribute__((ext_vector_type(4))) float floatx4;
typedef __attribute__((ext_vector_type(16))) float floatx16;
typedef __attribute__((ext_vector_type(4))) unsigned short ushort4v;
typedef __attribute__((ext_vector_type(8))) unsigned short ushort8v;

// ---------- sizes ----------
#define Bz 4096
#define Dz 256
#define Nz 128
#define Fz 128
#define Oz 256

// ---------- workspace layout (bytes) ----------
static constexpr size_t OFF_CONN = 0;                                   // 32 KB bf16 conn
static constexpr size_t OFF_WT   = 65536;                               // WT[n][c:128][k:384] bf16
static constexpr size_t SZ_WT    = (size_t)Nz * 128 * 384 * 2;          // 12582912
static constexpr size_t OFF_OWT  = OFF_WT + SZ_WT;                      // out_wT[o:256][f:128] bf16 (64 KB)
static constexpr size_t OFF_XB   = OFF_OWT + 65536;                     // x bf16 (4096x256, 2 MB)
static constexpr size_t OFF_FIN  = OFF_XB + (size_t)Bz * Dz * 2;        // final bf16 (4096x128, 1 MB)
static constexpr size_t OFF_ST   = OFF_FIN + (size_t)Bz * Fz * 2;       // state bf16 [n][b][f] (128 MB)

// ---------- helpers ----------
DEV unsigned short f2bf(float x) {
    unsigned u = __float_as_uint(x);
    u = (u + 0x7FFFu + ((u >> 16) & 1u)) >> 16;
    return (unsigned short)u;
}
DEV float bf2f(unsigned short h) {
    return __uint_as_float(((unsigned)h) << 16);
}

typedef const __attribute__((address_space(1))) void cglobal_void;
typedef __attribute__((address_space(3))) void lds_void;

DEV void gld_lds16(const void* g, void* l) {
    __builtin_amdgcn_global_load_lds((cglobal_void*)g, (lds_void*)l, 16, 0, 0);
}

// ---------- K_PREP: all 4 prep ops in one launch (block-range dispatch) ----------
__global__ __launch_bounds__(256) void k_prep(const float* __restrict__ nw, unsigned short* __restrict__ WT,
                                              const float* __restrict__ ow, unsigned short* __restrict__ OWT,
                                              const float* __restrict__ x, unsigned short* __restrict__ XB,
                                              const float* __restrict__ att, unsigned short* __restrict__ conn) {
    __shared__ float ld[32][36];
    int bid = blockIdx.x, t = threadIdx.x;
    if (bid < 6144) {
        int batch = bid / 48, rem = bid % 48;
        int rt = rem / 4, ct = rem % 4;
        int kr = t >> 3, c4 = (t & 7) * 4;
        float4 v = *(const float4*)&nw[(size_t)batch * (384 * 128) + (size_t)(rt * 32 + kr) * 128 + ct * 32 + c4];
        ld[kr][c4 + 0] = v.x; ld[kr][c4 + 1] = v.y; ld[kr][c4 + 2] = v.z; ld[kr][c4 + 3] = v.w;
        __syncthreads();
        ushort4v o;
        o[0] = f2bf(ld[c4 + 0][kr]);
        o[1] = f2bf(ld[c4 + 1][kr]);
        o[2] = f2bf(ld[c4 + 2][kr]);
        o[3] = f2bf(ld[c4 + 3][kr]);
        *(ushort4v*)&WT[(size_t)batch * (128 * 384) + (size_t)(ct * 32 + kr) * 384 + rt * 32 + c4] = o;
    } else if (bid < 6176) {
        int rem = bid - 6144;
        int rt = rem / 8, ct = rem % 8;
        int kr = t >> 3, c4 = (t & 7) * 4;
        float4 v = *(const float4*)&ow[(size_t)(rt * 32 + kr) * 256 + ct * 32 + c4];
        ld[kr][c4 + 0] = v.x; ld[kr][c4 + 1] = v.y; ld[kr][c4 + 2] = v.z; ld[kr][c4 + 3] = v.w;
        __syncthreads();
        ushort4v o;
        o[0] = f2bf(ld[c4 + 0][kr]);
        o[1] = f2bf(ld[c4 + 1][kr]);
        o[2] = f2bf(ld[c4 + 2][kr]);
        o[3] = f2bf(ld[c4 + 3][kr]);
        *(ushort4v*)&OWT[(size_t)(ct * 32 + kr) * 128 + rt * 32 + c4] = o;
    } else if (bid < 7200) {
        size_t idx = ((size_t)(bid - 6176) * 256 + t) * 4;
        float4 v = *(const float4*)&x[idx];
        ushort4v o;
        o[0] = f2bf(v.x); o[1] = f2bf(v.y); o[2] = f2bf(v.z); o[3] = f2bf(v.w);
        *(ushort4v*)&XB[idx] = o;
    } else if (t < 64) {
        int i = bid - 7200;
        float a0 = att[i * 128 + t];
        float a1 = att[i * 128 + 64 + t];
        float m = fmaxf(a0, a1);
        for (int o = 32; o > 0; o >>= 1) m = fmaxf(m, __shfl_down(m, o));
        m = __shfl(m, 0);
        float e0 = __expf(a0 - m), e1 = __expf(a1 - m);
        float s = e0 + e1;
        for (int o = 32; o > 0; o >>= 1) s += __shfl_down(s, o);
        s = __shfl(s, 0);
        float inv = 1.f / s;
        conn[i * 128 + t] = f2bf(e0 * inv);
        conn[i * 128 + 64 + t] = f2bf(e1 * inv);
    }
}

// ---------- K2 (in-place): ST[i][b][f] = sum_j conn[i][j] * ST[j][b][f] ----------
// Round-8 v4 (52.5 µs measured; ~81% of BW floor). Unchanged (passing).
__global__ __launch_bounds__(256) void k2_agg(const unsigned short* __restrict__ conn,
                                              unsigned short* __restrict__ ST) {
    __shared__ unsigned short lA[128 * 136];   // conn, padded rows (+8); reused as out tile
    __shared__ unsigned short lB[2][32 * 128]; // double-buffered states tile [j][f]
    int b = blockIdx.x;
    int t = threadIdx.x, wid = t >> 6, lane = t & 63, q = lane >> 4, cc = lane & 15;
    int wm = (wid >> 1) << 6, wn = (wid & 1) << 6;

    auto STG = [&](int bufi, int kt) {
#pragma unroll
        for (int it = 0; it < 2; it++) {
            int g = it * 256 + t;
            int j = g >> 4, fg = g & 15;
            int lofs = __builtin_amdgcn_readfirstlane((it * 256 + (wid << 6)) * 8);
            gld_lds16(ST + ((size_t)(kt * 32 + j) * Bz + b) * Fz + fg * 8, &lB[bufi][0] + lofs);
        }
    };
    STG(0, 0);
    STG(1, 1);

#pragma unroll
    for (int it = 0; it < 8; it++) {
        int g = it * 256 + t;
        int row = g >> 4, cg = g & 15;
        *(short8*)&lA[row * 136 + cg * 8] = *(const short8*)&conn[row * 128 + cg * 8];
    }
    floatx4 acc[4][4];
#pragma unroll
    for (int mt = 0; mt < 4; mt++)
#pragma unroll
        for (int nt = 0; nt < 4; nt++) acc[mt][nt] = (floatx4){0.f, 0.f, 0.f, 0.f};

    for (int kt = 0; kt < 4; kt++) {
        int cur = kt & 1;
        if (kt < 3) asm volatile("s_waitcnt vmcnt(2) lgkmcnt(0)" ::: "memory");
        else        asm volatile("s_waitcnt vmcnt(0) lgkmcnt(0)" ::: "memory");
        __builtin_amdgcn_s_barrier();
        short8 af[4];
#pragma unroll
        for (int mt = 0; mt < 4; mt++)
            af[mt] = *(const short8*)&lA[(wm + mt * 16 + cc) * 136 + kt * 32 + q * 8];
        short8 bf[4];
#pragma unroll
        for (int nt = 0; nt < 4; nt++) {
            short8 v;
#pragma unroll
            for (int e = 0; e < 8; e++)
                v[e] = (short)lB[cur][(q * 8 + e) * 128 + wn + nt * 16 + cc];
            bf[nt] = v;
        }
#pragma unroll
        for (int mt = 0; mt < 4; mt++)
#pragma unroll
            for (int nt = 0; nt < 4; nt++)
                acc[mt][nt] = __builtin_amdgcn_mfma_f32_16x16x32_bf16(af[mt], bf[nt], acc[mt][nt], 0, 0, 0);
        __builtin_amdgcn_s_barrier();          // all waves done reading lB[cur]
        if (kt + 2 < 4) STG(cur, kt + 2);      // overwrite freed buffer
    }

    // epilogue: stage XOR-swizzled [i][f] tile in lA, then coalesced 16B row stores
#pragma unroll
    for (int mt = 0; mt < 4; mt++)
#pragma unroll
        for (int nt = 0; nt < 4; nt++) {
            int f = wn + nt * 16 + cc;
#pragma unroll
            for (int r = 0; r < 4; r++) {
                int il = wm + mt * 16 + q * 4 + r;
                lA[il * 128 + (f ^ ((il & 7) << 3))] = f2bf(acc[mt][nt][r]);
            }
        }
    __syncthreads();
#pragma unroll
    for (int it = 0; it < 8; it++) {
        int idx = it * 256 + t;
        int il = idx >> 4, ch = idx & 15;
        int sch = ch ^ (il & 7);
        ushort8v v = *(const ushort8v*)&lA[il * 128 + sch * 8];
        *(ushort8v*)&ST[((size_t)il * Bz + b) * Fz + ch * 8] = v;
    }
}

// ---------- K3 fused (in-place): ST[n] = relu([agg | x] @ W[n] + bias) ----------
// v12 = v11 (32x32x16 MFMA, 2x2 wave grid of 64x64 tiles, fewer LDS reads/FLOP)
// + CHUNK-ROTATION swizzle to kill v11's 16-way fragment-read bank conflict:
// row r stores its four 16B k-chunks rotated by r (logical chunk c at position
// (c+r)&3). Applied source-side for global_load_lds (LINEAR LDS dest; the
// permutation stays within one 64B global line per 4-lane group, preserving
// coalescing) and read-side with the matching rotation. Bank-start for a
// fragment read becomes 16*(r&1)+4*((c+r)&3): 8 starts x 8 lanes spanning all
// 32 banks -> structural-optimal. Math bit-identical to v11 (chunk reorder only).
// Staging/sync: round-2 proven 4-gld/thread, 2 buffers, counted vmcnt(4).
// In-place safe: all ST reads precede writes; blocks disjoint (n, bt).
template <int KT0>
__global__ __launch_bounds__(256) void k3_fused(unsigned short* __restrict__ ST,
                                                const unsigned short* __restrict__ XB,
                                                const unsigned short* __restrict__ WT,
                                                const float* __restrict__ nb) {
    __shared__ unsigned short lds[2][2][128 * 32];  // [buf][A=0/B=1][row*32+k] — 32 KB
    int n = blockIdx.x >> 5, bt = blockIdx.x & 31;
    int t = threadIdx.x, wid = t >> 6, lane = t & 63;
    int r32 = lane & 31, kh = lane >> 5;            // row-in-32, k-half (0/1)
    int wm = (wid >> 1) << 6, wn = (wid & 1) << 6;  // 2x2 wave grid of 64x64 tiles

    const unsigned short* Sg = ST + ((size_t)n * Bz + bt * 128) * Fz;   // ld Fz
    const unsigned short* Xg = XB + (size_t)bt * 128 * Dz;              // ld Dz
    const unsigned short* Bg = WT + (size_t)n * 128 * 384;              // ld 384

    floatx16 acc[2][2];
#pragma unroll
    for (int mt = 0; mt < 2; mt++)
#pragma unroll
        for (int nt = 0; nt < 2; nt++)
#pragma unroll
            for (int e = 0; e < 16; e++) acc[mt][nt][e] = 0.f;

    // stage with source-side chunk rotation: LDS position kg of row holds
    // logical chunk (kg - row)&3.
    auto STAGE = [&](int bufi, int kt) {
#pragma unroll
        for (int it = 0; it < 2; it++) {
            int g = it * 256 + t;
            int row = g >> 2, kg = g & 3;
            int kgs = (kg - row) & 3;
            int lofs = __builtin_amdgcn_readfirstlane((it * 256 + (wid << 6)) * 8);
            if (kt < 4)
                gld_lds16(Sg + (size_t)row * Fz + kt * 32 + kgs * 8, &lds[bufi][0][0] + lofs);
            else
                gld_lds16(Xg + (size_t)row * Dz + (kt - 4) * 32 + kgs * 8, &lds[bufi][0][0] + lofs);
            gld_lds16(Bg + (size_t)row * 384 + kt * 32 + kgs * 8, &lds[bufi][1][0] + lofs);
        }
    };
    STAGE(0, KT0);
    STAGE(1, KT0 + 1);

#pragma unroll
    for (int kt = KT0; kt < 12; kt++) {
        int cur = (kt - KT0) & 1;
        // oldest 4 gld (stage kt) retired; stage kt+1's 4 stay in flight.
        if (kt < 11) asm volatile("s_waitcnt vmcnt(4) lgkmcnt(0)" ::: "memory");
        else         asm volatile("s_waitcnt vmcnt(0) lgkmcnt(0)" ::: "memory");
        __builtin_amdgcn_s_barrier();
        __builtin_amdgcn_sched_barrier(0);
        short8 af[2][2], bfr[2][2];   // [kq][tile]
#pragma unroll
        for (int kq = 0; kq < 2; kq++) {
            int c = kq * 2 + kh;                       // logical chunk
            int p = (c + r32) & 3;                     // rotated position
#pragma unroll
            for (int mt = 0; mt < 2; mt++)
                af[kq][mt] = *(const short8*)&lds[cur][0][(wm + mt * 32 + r32) * 32 + p * 8];
#pragma unroll
            for (int nt = 0; nt < 2; nt++)
                bfr[kq][nt] = *(const short8*)&lds[cur][1][(wn + nt * 32 + r32) * 32 + p * 8];
        }
#pragma unroll
        for (int kq = 0; kq < 2; kq++)
#pragma unroll
            for (int mt = 0; mt < 2; mt++)
#pragma unroll
                for (int nt = 0; nt < 2; nt++)
                    acc[mt][nt] = __builtin_amdgcn_mfma_f32_32x32x16_bf16(af[kq][mt], bfr[kq][nt], acc[mt][nt], 0, 0, 0);
        __builtin_amdgcn_sched_barrier(0);
        __builtin_amdgcn_s_barrier();           // all waves done reading lds[cur]
        if (kt + 2 < 12) STAGE(cur, kt + 2);    // overwrite freed buffer
    }

    // epilogue: bias+relu -> XOR-swizzled [b_local][f] tile (all 32 KB of lds),
    // then coalesced 16B contiguous stores. C/D map: col=r32, row=(reg&3)+8*(reg>>2)+4*kh.
    __syncthreads();
    unsigned short* outT = &lds[0][0][0];
#pragma unroll
    for (int nt = 0; nt < 2; nt++) {
        int f = wn + nt * 32 + r32;
        float bias = nb[n * Fz + f];
#pragma unroll
        for (int mt = 0; mt < 2; mt++) {
#pragma unroll
            for (int reg = 0; reg < 16; reg++) {
                int bl = wm + mt * 32 + (reg & 3) + 8 * (reg >> 2) + 4 * kh;
                float v = acc[mt][nt][reg] + bias;
                outT[bl * 128 + (f ^ ((bl & 7) << 3))] = f2bf(v > 0.f ? v : 0.f);
            }
        }
    }
    __syncthreads();
    size_t base = ((size_t)n * Bz + (size_t)bt * 128) * Fz;
#pragma unroll
    for (int it = 0; it < 8; it++) {
        int idx = it * 256 + t;
        int bl = idx >> 4, ch = idx & 15;
        int sch = ch ^ (bl & 7);
        ushort8v v = *(const ushort8v*)&outT[bl * 128 + sch * 8];
        *(ushort8v*)&ST[base + (size_t)idx * 8] = v;
    }
}

// ---------- K4: final[b][f] = mean_n ST[n][b][f] ----------
__global__ __launch_bounds__(256) void k4_mean(const unsigned short* __restrict__ S,
                                               unsigned short* __restrict__ fin) {
    int t = threadIdx.x;
    size_t base = (size_t)blockIdx.x * 2048 + (size_t)t * 8;
    float a[8] = {0.f, 0.f, 0.f, 0.f, 0.f, 0.f, 0.f, 0.f};
#pragma unroll 8
    for (int n = 0; n < Nz; n++) {
        ushort8v v = *(const ushort8v*)&S[(size_t)n * Bz * Fz + base];
#pragma unroll
        for (int e = 0; e < 8; e++) a[e] += bf2f(v[e]);
    }
    ushort8v o;
#pragma unroll
    for (int e = 0; e < 8; e++) o[e] = f2bf(a[e] * (1.f / 128.f));
    *(ushort8v*)&fin[base] = o;
}

// ---------- K5: out = final @ out_w + out_b (fp32 out) ----------
__global__ __launch_bounds__(256) void k5_out(const unsigned short* __restrict__ fin,
                                              const unsigned short* __restrict__ owt,
                                              const float* __restrict__ ob,
                                              float* __restrict__ out) {
    __shared__ unsigned short lA[128 * 32];
    __shared__ unsigned short lB[128 * 32];
    int bt = blockIdx.x >> 1, ct = blockIdx.x & 1;
    int t = threadIdx.x, wid = t >> 6, lane = t & 63, q = lane >> 4, cc = lane & 15;
    int wm = (wid >> 1) << 6, wn = (wid & 1) << 6;

    const unsigned short* Ag = fin + (size_t)bt * 128 * Fz;
    const unsigned short* Bg = owt + (size_t)ct * 128 * Fz;

    floatx4 acc[4][4];
#pragma unroll
    for (int mt = 0; mt < 4; mt++)
#pragma unroll
        for (int nt = 0; nt < 4; nt++) acc[mt][nt] = (floatx4){0.f, 0.f, 0.f, 0.f};

    for (int kt = 0; kt < 4; kt++) {
#pragma unroll
        for (int it = 0; it < 2; it++) {
            int g = it * 256 + t;
            int row = g >> 2, kg = g & 3;
            int lofs = __builtin_amdgcn_readfirstlane((it * 256 + (wid << 6)) * 8);
            gld_lds16(Ag + (size_t)row * Fz + kt * 32 + kg * 8, lA + lofs);
            gld_lds16(Bg + (size_t)row * Fz + kt * 32 + kg * 8, lB + lofs);
        }
        __syncthreads();
        short8 af[4], bfr[4];
#pragma unroll
        for (int mt = 0; mt < 4; mt++)
            af[mt] = *(const short8*)&lA[(wm + mt * 16 + cc) * 32 + q * 8];
#pragma unroll
        for (int nt = 0; nt < 4; nt++)
            bfr[nt] = *(const short8*)&lB[(wn + nt * 16 + cc) * 32 + q * 8];
#pragma unroll
        for (int mt = 0; mt < 4; mt++)
#pragma unroll
            for (int nt = 0; nt < 4; nt++)
                acc[mt][nt] = __builtin_amdgcn_mfma_f32_16x16x32_bf16(af[mt], bfr[nt], acc[mt][nt], 0, 0, 0);
        __syncthreads();
    }
#pragma unroll
    for (int nt = 0; nt < 4; nt++) {
        int o = ct * 128 + wn + nt * 16 + cc;
        float bias = ob[o];
#pragma unroll
        for (int mt = 0; mt < 4; mt++) {
#pragma unroll
            for (int r = 0; r < 4; r++) {
                int b = bt * 128 + wm + mt * 16 + q * 4 + r;
                out[(size_t)b * Oz + o] = acc[mt][nt][r] + bias;
            }
        }
    }
}

extern "C" void kernel_launch(void* const* d_in, const int* in_sizes, int n_in,
                              void* d_out, int out_size, void* d_ws, size_t ws_size,
                              hipStream_t stream) {
    const float* x = (const float*)d_in[0];
    const float* nw = (const float*)d_in[1];
    const float* nb = (const float*)d_in[2];
    const float* att = (const float*)d_in[3];
    const float* ow = (const float*)d_in[4];
    const float* ob = (const float*)d_in[5];
    char* ws = (char*)d_ws;
    unsigned short* CONN = (unsigned short*)(ws + OFF_CONN);
    unsigned short* WT = (unsigned short*)(ws + OFF_WT);
    unsigned short* OWT = (unsigned short*)(ws + OFF_OWT);
    unsigned short* XB = (unsigned short*)(ws + OFF_XB);
    unsigned short* FIN = (unsigned short*)(ws + OFF_FIN);
    unsigned short* ST = (unsigned short*)(ws + OFF_ST);
    float* out = (float*)d_out;

    // prep: one launch for softmax + both transposes + convert
    k_prep<<<7328, 256, 0, stream>>>(nw, WT, ow, OWT, x, XB, att, CONN);

    // iteration 1: ST = relu(x @ W_x + b)   (state0 == 0 -> skip state k-steps)
    k3_fused<4><<<Nz * 32, 256, 0, stream>>>(ST, XB, WT, nb);

    // iterations 2 and 3: in-place agg then fused update
    for (int it = 0; it < 2; it++) {
        k2_agg<<<Bz, 256, 0, stream>>>(CONN, ST);
        k3_fused<0><<<Nz * 32, 256, 0, stream>>>(ST, XB, WT, nb);
    }

    k4_mean<<<(Bz * Fz) / 2048, 256, 0, stream>>>(ST, FIN);
    k5_out<<<64, 256, 0, stream>>>(FIN, OWT, ob, out);
}

// Round 16
// 389.454 us; speedup vs baseline: 1.0626x; 1.0559x over previous
//
#include <hip/hip_runtime.h>

#define DEV __device__ __forceinline__

typedef __attribute__((ext_vector_type(8))) short short8;
typedef __attribute__((ext_vector_type(4))) float floatx4;
typedef __attribute__((ext_vector_type(4))) unsigned short ushort4v;
typedef __attribute__((ext_vector_type(8))) unsigned short ushort8v;

// ---------- sizes ----------
#define Bz 4096
#define Dz 256
#define Nz 128
#define Fz 128
#define Oz 256

// ---------- workspace layout (bytes) ----------
static constexpr size_t OFF_CONN = 0;                                   // 32 KB bf16 conn
static constexpr size_t OFF_WT   = 65536;                               // WT[n][c:128][k:384] bf16
static constexpr size_t SZ_WT    = (size_t)Nz * 128 * 384 * 2;          // 12582912
static constexpr size_t OFF_OWT  = OFF_WT + SZ_WT;                      // out_wT[o:256][f:128] bf16 (64 KB)
static constexpr size_t OFF_XB   = OFF_OWT + 65536;                     // x bf16 (4096x256, 2 MB)
static constexpr size_t OFF_FIN  = OFF_XB + (size_t)Bz * Dz * 2;        // final bf16 (4096x128, 1 MB)
static constexpr size_t OFF_ST   = OFF_FIN + (size_t)Bz * Fz * 2;       // state bf16 [n][b][f] (128 MB)

// ---------- helpers ----------
DEV unsigned short f2bf(float x) {
    unsigned u = __float_as_uint(x);
    u = (u + 0x7FFFu + ((u >> 16) & 1u)) >> 16;
    return (unsigned short)u;
}
DEV float bf2f(unsigned short h) {
    return __uint_as_float(((unsigned)h) << 16);
}

typedef const __attribute__((address_space(1))) void cglobal_void;
typedef __attribute__((address_space(3))) void lds_void;

DEV void gld_lds16(const void* g, void* l) {
    __builtin_amdgcn_global_load_lds((cglobal_void*)g, (lds_void*)l, 16, 0, 0);
}

// ---------- K_PREP: all 4 prep ops in one launch (block-range dispatch) ----------
__global__ __launch_bounds__(256) void k_prep(const float* __restrict__ nw, unsigned short* __restrict__ WT,
                                              const float* __restrict__ ow, unsigned short* __restrict__ OWT,
                                              const float* __restrict__ x, unsigned short* __restrict__ XB,
                                              const float* __restrict__ att, unsigned short* __restrict__ conn) {
    __shared__ float ld[32][36];
    int bid = blockIdx.x, t = threadIdx.x;
    if (bid < 6144) {
        int batch = bid / 48, rem = bid % 48;
        int rt = rem / 4, ct = rem % 4;
        int kr = t >> 3, c4 = (t & 7) * 4;
        float4 v = *(const float4*)&nw[(size_t)batch * (384 * 128) + (size_t)(rt * 32 + kr) * 128 + ct * 32 + c4];
        ld[kr][c4 + 0] = v.x; ld[kr][c4 + 1] = v.y; ld[kr][c4 + 2] = v.z; ld[kr][c4 + 3] = v.w;
        __syncthreads();
        ushort4v o;
        o[0] = f2bf(ld[c4 + 0][kr]);
        o[1] = f2bf(ld[c4 + 1][kr]);
        o[2] = f2bf(ld[c4 + 2][kr]);
        o[3] = f2bf(ld[c4 + 3][kr]);
        *(ushort4v*)&WT[(size_t)batch * (128 * 384) + (size_t)(ct * 32 + kr) * 384 + rt * 32 + c4] = o;
    } else if (bid < 6176) {
        int rem = bid - 6144;
        int rt = rem / 8, ct = rem % 8;
        int kr = t >> 3, c4 = (t & 7) * 4;
        float4 v = *(const float4*)&ow[(size_t)(rt * 32 + kr) * 256 + ct * 32 + c4];
        ld[kr][c4 + 0] = v.x; ld[kr][c4 + 1] = v.y; ld[kr][c4 + 2] = v.z; ld[kr][c4 + 3] = v.w;
        __syncthreads();
        ushort4v o;
        o[0] = f2bf(ld[c4 + 0][kr]);
        o[1] = f2bf(ld[c4 + 1][kr]);
        o[2] = f2bf(ld[c4 + 2][kr]);
        o[3] = f2bf(ld[c4 + 3][kr]);
        *(ushort4v*)&OWT[(size_t)(ct * 32 + kr) * 128 + rt * 32 + c4] = o;
    } else if (bid < 7200) {
        size_t idx = ((size_t)(bid - 6176) * 256 + t) * 4;
        float4 v = *(const float4*)&x[idx];
        ushort4v o;
        o[0] = f2bf(v.x); o[1] = f2bf(v.y); o[2] = f2bf(v.z); o[3] = f2bf(v.w);
        *(ushort4v*)&XB[idx] = o;
    } else if (t < 64) {
        int i = bid - 7200;
        float a0 = att[i * 128 + t];
        float a1 = att[i * 128 + 64 + t];
        float m = fmaxf(a0, a1);
        for (int o = 32; o > 0; o >>= 1) m = fmaxf(m, __shfl_down(m, o));
        m = __shfl(m, 0);
        float e0 = __expf(a0 - m), e1 = __expf(a1 - m);
        float s = e0 + e1;
        for (int o = 32; o > 0; o >>= 1) s += __shfl_down(s, o);
        s = __shfl(s, 0);
        float inv = 1.f / s;
        conn[i * 128 + t] = f2bf(e0 * inv);
        conn[i * 128 + 64 + t] = f2bf(e1 * inv);
    }
}

// ---------- K2 (in-place): ST[i][b][f] = sum_j conn[i][j] * ST[j][b][f] ----------
// Round-8 v4 (52.5 µs measured; ~81% of BW floor). Unchanged (passing).
__global__ __launch_bounds__(256) void k2_agg(const unsigned short* __restrict__ conn,
                                              unsigned short* __restrict__ ST) {
    __shared__ unsigned short lA[128 * 136];   // conn, padded rows (+8); reused as out tile
    __shared__ unsigned short lB[2][32 * 128]; // double-buffered states tile [j][f]
    int b = blockIdx.x;
    int t = threadIdx.x, wid = t >> 6, lane = t & 63, q = lane >> 4, cc = lane & 15;
    int wm = (wid >> 1) << 6, wn = (wid & 1) << 6;

    auto STG = [&](int bufi, int kt) {
#pragma unroll
        for (int it = 0; it < 2; it++) {
            int g = it * 256 + t;
            int j = g >> 4, fg = g & 15;
            int lofs = __builtin_amdgcn_readfirstlane((it * 256 + (wid << 6)) * 8);
            gld_lds16(ST + ((size_t)(kt * 32 + j) * Bz + b) * Fz + fg * 8, &lB[bufi][0] + lofs);
        }
    };
    STG(0, 0);
    STG(1, 1);

#pragma unroll
    for (int it = 0; it < 8; it++) {
        int g = it * 256 + t;
        int row = g >> 4, cg = g & 15;
        *(short8*)&lA[row * 136 + cg * 8] = *(const short8*)&conn[row * 128 + cg * 8];
    }
    floatx4 acc[4][4];
#pragma unroll
    for (int mt = 0; mt < 4; mt++)
#pragma unroll
        for (int nt = 0; nt < 4; nt++) acc[mt][nt] = (floatx4){0.f, 0.f, 0.f, 0.f};

    for (int kt = 0; kt < 4; kt++) {
        int cur = kt & 1;
        if (kt < 3) asm volatile("s_waitcnt vmcnt(2) lgkmcnt(0)" ::: "memory");
        else        asm volatile("s_waitcnt vmcnt(0) lgkmcnt(0)" ::: "memory");
        __builtin_amdgcn_s_barrier();
        short8 af[4];
#pragma unroll
        for (int mt = 0; mt < 4; mt++)
            af[mt] = *(const short8*)&lA[(wm + mt * 16 + cc) * 136 + kt * 32 + q * 8];
        short8 bf[4];
#pragma unroll
        for (int nt = 0; nt < 4; nt++) {
            short8 v;
#pragma unroll
            for (int e = 0; e < 8; e++)
                v[e] = (short)lB[cur][(q * 8 + e) * 128 + wn + nt * 16 + cc];
            bf[nt] = v;
        }
#pragma unroll
        for (int mt = 0; mt < 4; mt++)
#pragma unroll
            for (int nt = 0; nt < 4; nt++)
                acc[mt][nt] = __builtin_amdgcn_mfma_f32_16x16x32_bf16(af[mt], bf[nt], acc[mt][nt], 0, 0, 0);
        __builtin_amdgcn_s_barrier();          // all waves done reading lB[cur]
        if (kt + 2 < 4) STG(cur, kt + 2);      // overwrite freed buffer
    }

    // epilogue: stage XOR-swizzled [i][f] tile in lA, then coalesced 16B row stores
#pragma unroll
    for (int mt = 0; mt < 4; mt++)
#pragma unroll
        for (int nt = 0; nt < 4; nt++) {
            int f = wn + nt * 16 + cc;
#pragma unroll
            for (int r = 0; r < 4; r++) {
                int il = wm + mt * 16 + q * 4 + r;
                lA[il * 128 + (f ^ ((il & 7) << 3))] = f2bf(acc[mt][nt][r]);
            }
        }
    __syncthreads();
#pragma unroll
    for (int it = 0; it < 8; it++) {
        int idx = it * 256 + t;
        int il = idx >> 4, ch = idx & 15;
        int sch = ch ^ (il & 7);
        ushort8v v = *(const ushort8v*)&lA[il * 128 + sch * 8];
        *(ushort8v*)&ST[((size_t)il * Bz + b) * Fz + ch * 8] = v;
    }
}

// ---------- K3 fused (in-place): ST[n] = relu([agg | x] @ W[n] + bias) ----------
// v13 = round-11 v8 (512 thr / 8 waves, 64x32 wave tile, acc[4][2], 36 VGPR,
// 2-buffer 32 KB, counted vmcnt(2)) WITHOUT the sched_barrier(0) pins.
// Motivation: k2's single biggest win (73->52.5 µs) was removing these exact
// pins at identical barrier/vmcnt structure; k3 carried them in every variant.
// Barriers are asm s_barrier with "memory" clobber: no LDS read can hoist above
// the acquire barrier (cross-wave DMA completion) and no STAGE gld above the
// release barrier. Compiler is otherwise free to interleave reads/MFMA.
// In-place safe: all ST reads precede writes; blocks disjoint (n, bt).
template <int KT0>
__global__ __launch_bounds__(512) void k3_fused(unsigned short* __restrict__ ST,
                                                const unsigned short* __restrict__ XB,
                                                const unsigned short* __restrict__ WT,
                                                const float* __restrict__ nb) {
    __shared__ unsigned short lds[2][2][128 * 32];  // [buf][A=0/B=1][row*32+k] — 32 KB
    int n = blockIdx.x >> 5, bt = blockIdx.x & 31;
    int t = threadIdx.x, wid = t >> 6, lane = t & 63, q = lane >> 4, cc = lane & 15;
    int wm = (wid >> 2) << 6;   // 0 or 64   (2 row-groups)
    int wn = (wid & 3) << 5;    // 0,32,64,96 (4 col-groups)

    const unsigned short* Sg = ST + ((size_t)n * Bz + bt * 128) * Fz;   // ld Fz
    const unsigned short* Xg = XB + (size_t)bt * 128 * Dz;              // ld Dz
    const unsigned short* Bg = WT + (size_t)n * 128 * 384;              // ld 384

    floatx4 acc[4][2];
#pragma unroll
    for (int mt = 0; mt < 4; mt++)
#pragma unroll
        for (int nt = 0; nt < 2; nt++) acc[mt][nt] = (floatx4){0.f, 0.f, 0.f, 0.f};

    // one K-step tile: A 128x32 (1 shot, 512 x 16B) + B 128x32 (1 shot); 2 gld/thread
    auto STAGE = [&](int bufi, int kt) {
        int row = t >> 2, kg = t & 3;
        int lofs = __builtin_amdgcn_readfirstlane(wid << 9);  // wid*512 ush = wid*1KB
        if (kt < 4)
            gld_lds16(Sg + (size_t)row * Fz + kt * 32 + kg * 8, &lds[bufi][0][0] + lofs);
        else
            gld_lds16(Xg + (size_t)row * Dz + (kt - 4) * 32 + kg * 8, &lds[bufi][0][0] + lofs);
        gld_lds16(Bg + (size_t)row * 384 + kt * 32 + kg * 8, &lds[bufi][1][0] + lofs);
    };
    STAGE(0, KT0);
    STAGE(1, KT0 + 1);

#pragma unroll
    for (int kt = KT0; kt < 12; kt++) {
        int cur = (kt - KT0) & 1;
        // oldest 2 gld (stage kt) retired; stage kt+1's 2 stay in flight.
        if (kt < 11) asm volatile("s_waitcnt vmcnt(2) lgkmcnt(0)" ::: "memory");
        else         asm volatile("s_waitcnt vmcnt(0) lgkmcnt(0)" ::: "memory");
        asm volatile("s_barrier" ::: "memory");     // acquire: all waves' stage(kt) landed
        short8 af[4], bfr[2];
#pragma unroll
        for (int mt = 0; mt < 4; mt++)
            af[mt] = *(const short8*)&lds[cur][0][(wm + mt * 16 + cc) * 32 + q * 8];
#pragma unroll
        for (int nt = 0; nt < 2; nt++)
            bfr[nt] = *(const short8*)&lds[cur][1][(wn + nt * 16 + cc) * 32 + q * 8];
#pragma unroll
        for (int mt = 0; mt < 4; mt++)
#pragma unroll
            for (int nt = 0; nt < 2; nt++)
                acc[mt][nt] = __builtin_amdgcn_mfma_f32_16x16x32_bf16(af[mt], bfr[nt], acc[mt][nt], 0, 0, 0);
        asm volatile("s_barrier" ::: "memory");     // release: all waves done reading lds[cur]
        if (kt + 2 < 12) STAGE(cur, kt + 2);        // overwrite freed buffer
    }

    // epilogue: bias+relu -> XOR-swizzled [b_local][f] tile (all 32 KB of lds),
    // then coalesced 16B contiguous stores (128x128 region contiguous in ST).
    unsigned short* outT = &lds[0][0][0];   // 16384 ush = 32 KB
#pragma unroll
    for (int nt = 0; nt < 2; nt++) {
        int f = wn + nt * 16 + cc;
        float bias = nb[n * Fz + f];
#pragma unroll
        for (int mt = 0; mt < 4; mt++) {
#pragma unroll
            for (int r = 0; r < 4; r++) {
                int bl = wm + mt * 16 + q * 4 + r;
                float v = acc[mt][nt][r] + bias;
                outT[bl * 128 + (f ^ ((bl & 7) << 3))] = f2bf(v > 0.f ? v : 0.f);
            }
        }
    }
    __syncthreads();
    size_t base = ((size_t)n * Bz + (size_t)bt * 128) * Fz;
#pragma unroll
    for (int it = 0; it < 4; it++) {
        int idx = it * 512 + t;
        int bl = idx >> 4, ch = idx & 15;
        int sch = ch ^ (bl & 7);
        ushort8v v = *(const ushort8v*)&outT[bl * 128 + sch * 8];
        *(ushort8v*)&ST[base + (size_t)idx * 8] = v;
    }
}

// ---------- K4: final[b][f] = mean_n ST[n][b][f] ----------
__global__ __launch_bounds__(256) void k4_mean(const unsigned short* __restrict__ S,
                                               unsigned short* __restrict__ fin) {
    int t = threadIdx.x;
    size_t base = (size_t)blockIdx.x * 2048 + (size_t)t * 8;
    float a[8] = {0.f, 0.f, 0.f, 0.f, 0.f, 0.f, 0.f, 0.f};
#pragma unroll 8
    for (int n = 0; n < Nz; n++) {
        ushort8v v = *(const ushort8v*)&S[(size_t)n * Bz * Fz + base];
#pragma unroll
        for (int e = 0; e < 8; e++) a[e] += bf2f(v[e]);
    }
    ushort8v o;
#pragma unroll
    for (int e = 0; e < 8; e++) o[e] = f2bf(a[e] * (1.f / 128.f));
    *(ushort8v*)&fin[base] = o;
}

// ---------- K5: out = final @ out_w + out_b (fp32 out) ----------
__global__ __launch_bounds__(256) void k5_out(const unsigned short* __restrict__ fin,
                                              const unsigned short* __restrict__ owt,
                                              const float* __restrict__ ob,
                                              float* __restrict__ out) {
    __shared__ unsigned short lA[128 * 32];
    __shared__ unsigned short lB[128 * 32];
    int bt = blockIdx.x >> 1, ct = blockIdx.x & 1;
    int t = threadIdx.x, wid = t >> 6, lane = t & 63, q = lane >> 4, cc = lane & 15;
    int wm = (wid >> 1) << 6, wn = (wid & 1) << 6;

    const unsigned short* Ag = fin + (size_t)bt * 128 * Fz;
    const unsigned short* Bg = owt + (size_t)ct * 128 * Fz;

    floatx4 acc[4][4];
#pragma unroll
    for (int mt = 0; mt < 4; mt++)
#pragma unroll
        for (int nt = 0; nt < 4; nt++) acc[mt][nt] = (floatx4){0.f, 0.f, 0.f, 0.f};

    for (int kt = 0; kt < 4; kt++) {
#pragma unroll
        for (int it = 0; it < 2; it++) {
            int g = it * 256 + t;
            int row = g >> 2, kg = g & 3;
            int lofs = __builtin_amdgcn_readfirstlane((it * 256 + (wid << 6)) * 8);
            gld_lds16(Ag + (size_t)row * Fz + kt * 32 + kg * 8, lA + lofs);
            gld_lds16(Bg + (size_t)row * Fz + kt * 32 + kg * 8, lB + lofs);
        }
        __syncthreads();
        short8 af[4], bfr[4];
#pragma unroll
        for (int mt = 0; mt < 4; mt++)
            af[mt] = *(const short8*)&lA[(wm + mt * 16 + cc) * 32 + q * 8];
#pragma unroll
        for (int nt = 0; nt < 4; nt++)
            bfr[nt] = *(const short8*)&lB[(wn + nt * 16 + cc) * 32 + q * 8];
#pragma unroll
        for (int mt = 0; mt < 4; mt++)
#pragma unroll
            for (int nt = 0; nt < 4; nt++)
                acc[mt][nt] = __builtin_amdgcn_mfma_f32_16x16x32_bf16(af[mt], bfr[nt], acc[mt][nt], 0, 0, 0);
        __syncthreads();
    }
#pragma unroll
    for (int nt = 0; nt < 4; nt++) {
        int o = ct * 128 + wn + nt * 16 + cc;
        float bias = ob[o];
#pragma unroll
        for (int mt = 0; mt < 4; mt++) {
#pragma unroll
            for (int r = 0; r < 4; r++) {
                int b = bt * 128 + wm + mt * 16 + q * 4 + r;
                out[(size_t)b * Oz + o] = acc[mt][nt][r] + bias;
            }
        }
    }
}

extern "C" void kernel_launch(void* const* d_in, const int* in_sizes, int n_in,
                              void* d_out, int out_size, void* d_ws, size_t ws_size,
                              hipStream_t stream) {
    const float* x = (const float*)d_in[0];
    const float* nw = (const float*)d_in[1];
    const float* nb = (const float*)d_in[2];
    const float* att = (const float*)d_in[3];
    const float* ow = (const float*)d_in[4];
    const float* ob = (const float*)d_in[5];
    char* ws = (char*)d_ws;
    unsigned short* CONN = (unsigned short*)(ws + OFF_CONN);
    unsigned short* WT = (unsigned short*)(ws + OFF_WT);
    unsigned short* OWT = (unsigned short*)(ws + OFF_OWT);
    unsigned short* XB = (unsigned short*)(ws + OFF_XB);
    unsigned short* FIN = (unsigned short*)(ws + OFF_FIN);
    unsigned short* ST = (unsigned short*)(ws + OFF_ST);
    float* out = (float*)d_out;

    // prep: one launch for softmax + both transposes + convert
    k_prep<<<7328, 256, 0, stream>>>(nw, WT, ow, OWT, x, XB, att, CONN);

    // iteration 1: ST = relu(x @ W_x + b)   (state0 == 0 -> skip state k-steps)
    k3_fused<4><<<Nz * 32, 512, 0, stream>>>(ST, XB, WT, nb);

    // iterations 2 and 3: in-place agg then fused update
    for (int it = 0; it < 2; it++) {
        k2_agg<<<Bz, 256, 0, stream>>>(CONN, ST);
        k3_fused<0><<<Nz * 32, 512, 0, stream>>>(ST, XB, WT, nb);
    }

    k4_mean<<<(Bz * Fz) / 2048, 256, 0, stream>>>(ST, FIN);
    k5_out<<<64, 256, 0, stream>>>(FIN, OWT, ob, out);
}